// Round 7
// baseline (278.472 us; speedup 1.0000x reference)
//
#include <hip/hip_runtime.h>
#include <cstdint>
#include <cstddef>

using frag8 = __attribute__((ext_vector_type(8))) short;   // 8 bf16
using f32x4 = __attribute__((ext_vector_type(4))) float;

__device__ __forceinline__ float b2f_bits(unsigned short u) {
    union { uint32_t u32; float f; } x; x.u32 = ((uint32_t)u) << 16; return x.f;
}
__device__ __forceinline__ float b2f_lo(uint32_t pk) {
    return __builtin_bit_cast(float, pk << 16);
}
__device__ __forceinline__ float b2f_hi(uint32_t pk) {
    return __builtin_bit_cast(float, pk & 0xffff0000u);
}
__device__ __forceinline__ unsigned short f2b(float f) {   // RNE f32 -> bf16
    uint32_t u = __builtin_bit_cast(uint32_t, f);
    uint32_t r = (u + 0x7fffu + ((u >> 16) & 1u)) >> 16;
    return (unsigned short)r;
}
__device__ __forceinline__ uint32_t cvtpk_bf16(float lo, float hi) {   // RNE pack 2xf32->2xbf16
    uint32_t r;
    asm("v_cvt_pk_bf16_f32 %0, %1, %2" : "=v"(r) : "v"(lo), "v"(hi));
    return r;
}

#define HF 32
#define WFEAT 88
#define NCAM 6
#define NPT 102400
#define BM 128
#define BN 128
#define BK 64

// ================= merged prep: project + featT(LDS transpose) + casts + stats ========
__global__ __launch_bounds__(256) void k_prep(const float* __restrict__ feat,
                                              const float* __restrict__ pw2,
                                              const float* __restrict__ pw3,
                                              const float* __restrict__ c1w,
                                              const float* __restrict__ c2w,
                                              const float* __restrict__ c3w,
                                              const float* __restrict__ l2i,
                                              const float* __restrict__ bev,
                                              unsigned short* __restrict__ featT,
                                              unsigned short* __restrict__ W2Tb,
                                              unsigned short* __restrict__ W3Tb,
                                              unsigned short* __restrict__ C1Wb,
                                              unsigned short* __restrict__ C2Wb,
                                              unsigned short* __restrict__ C3Wb,
                                              float* __restrict__ stats,
                                              int* __restrict__ poff,
                                              float4* __restrict__ pwts) {
    __shared__ unsigned short tile[64 * 132];   // transpose tile (132 = 128 + pad)
    int b = blockIdx.x, t = threadIdx.x;
    if (b < 2400) {                       // ---- projection precompute (cam, point) ----
        int idx = b * 256 + t;            // n*NPT + pt, < 614400
        int n = idx / NPT, pt = idx - n * NPT;
        int q = pt >> 2, p = pt & 3;
        int h = q / 160, w = q - h * 160;
        const float* bv = bev + ((p * 160 + h) * 160 + w) * 3;
        float rx = bv[0] * 100.f - 50.f;
        float ry = bv[1] * 100.f - 50.f;
        float rz = bv[2] * 8.f - 4.f;
        const float* M = l2i + n * 16;
        float c0   = M[0] * rx + M[1] * ry + M[2]  * rz + M[3];
        float c1v  = M[4] * rx + M[5] * ry + M[6]  * rz + M[7];
        float homo = M[8] * rx + M[9] * ry + M[10] * rz + M[11];
        float z = fmaxf(homo, 1e-5f);
        float u = c0 / z / 704.0f;
        float v = c1v / z / 256.0f;
        if (!(homo > 1e-5f && u > 0.f && u < 1.f && v > 0.f && v < 1.f)) {
            poff[idx] = -1;
            return;
        }
        float fx = u * (float)WFEAT - 0.5f;
        float fy = v * (float)HF - 0.5f;
        float fx0 = floorf(fx), fy0 = floorf(fy);
        float dx = fx - fx0, dy = fy - fy0;
        int x0 = (int)fx0, y0 = (int)fy0;
        float wxa = (x0 < 0) ? dx : 1.f - dx;
        float wxb = (x0 >= 0 && x0 < WFEAT - 1) ? dx : 0.f;
        float wya = (y0 < 0) ? dy : 1.f - dy;
        float wyb = (y0 >= 0 && y0 < HF - 1) ? dy : 0.f;
        int bx = max(x0, 0), by = max(y0, 0);
        poff[idx] = ((n * HF + by) * WFEAT + bx) << 7;
        pwts[idx] = make_float4(wxa * wya, wxb * wya, wxa * wyb, wxb * wyb);
        return;
    }
    b -= 2400;
    if (b < 264) {                        // ---- feat -> featT via LDS tiled transpose ----
        int n = b / 44;
        int s0 = (b - n * 44) * 64;
        #pragma unroll
        for (int i = 0; i < 32; ++i) {
            int e = i * 256 + t;          // 8192 elems: c = e>>6, sl = e&63
            int c = e >> 6, sl = e & 63;
            tile[sl * 132 + c] = f2b(feat[(size_t)(n * 128 + c) * 2816 + s0 + sl]);
        }
        __syncthreads();
        #pragma unroll
        for (int j = 0; j < 8; ++j) {
            int flat = j * 1024 + t * 4;  // ushort4 chunks
            int sl = flat >> 7, c = flat & 127;
            ushort4 v = *(const ushort4*)(tile + sl * 132 + c);
            *(ushort4*)(featT + (size_t)(n * 2816 + s0 + sl) * 128 + c) = v;
        }
        return;
    }
    b -= 264;
    if (b < 256) {                        // ---- pw2 [256][256] -> W2Tb [o][k] ----
        int idx = b * 256 + t;
        int r = idx >> 8, c = idx & 255;
        W2Tb[c * 256 + r] = f2b(pw2[idx]);
        return;
    }
    b -= 256;
    if (b < 128) {                        // ---- pw3 [256][128] -> W3Tb [o][k] ----
        int idx = b * 256 + t;
        int r = idx >> 7, c = idx & 127;
        W3Tb[c * 256 + r] = f2b(pw3[idx]);
        return;
    }
    b -= 128;
    if (b < 1024) { int idx = b * 256 + t; C1Wb[idx] = f2b(c1w[idx]); return; }
    b -= 1024;
    if (b < 256)  { int idx = b * 256 + t; C2Wb[idx] = f2b(c2w[idx]); return; }
    b -= 256;
    if (b < 64)   { int idx = b * 256 + t; C3Wb[idx] = f2b(c3w[idx]); return; }
    // ---- stats zero (2560 floats: st512 @0, st128 @2048) ----
    #pragma unroll
    for (int j = 0; j < 10; ++j) stats[t * 10 + j] = 0.f;
}

// ---------------- gather-only sampling: one wave per point, lane = 2 channels ----------------
__global__ __launch_bounds__(256) void k_sample2(const unsigned short* __restrict__ featT,
                                                 const int* __restrict__ poff,
                                                 const float4* __restrict__ pwts,
                                                 unsigned short* __restrict__ samp) {
    int pt = blockIdx.x * 4 + (threadIdx.x >> 6);
    int lane = threadIdx.x & 63;
    int c2 = lane * 2;
    int offs[NCAM];
    float4 ww[NCAM];
    #pragma unroll
    for (int n = 0; n < NCAM; ++n) offs[n] = poff[n * NPT + pt];
    #pragma unroll
    for (int n = 0; n < NCAM; ++n) ww[n] = pwts[n * NPT + pt];   // garbage if invalid; unused
    float acc0 = 0.f, acc1 = 0.f;
    #pragma unroll
    for (int n = 0; n < NCAM; ++n) {
        if (offs[n] >= 0) {                        // wave-uniform scalar branch
            const unsigned short* base = featT + offs[n] + c2;
            uint32_t p00 = *(const uint32_t*)(base);
            uint32_t p01 = *(const uint32_t*)(base + 128);
            uint32_t p10 = *(const uint32_t*)(base + WFEAT * 128);
            uint32_t p11 = *(const uint32_t*)(base + WFEAT * 128 + 128);
            float4 w = ww[n];
            acc0 += w.x * b2f_lo(p00) + w.y * b2f_lo(p01) + w.z * b2f_lo(p10) + w.w * b2f_lo(p11);
            acc1 += w.x * b2f_hi(p00) + w.y * b2f_hi(p01) + w.z * b2f_hi(p10) + w.w * b2f_hi(p11);
        }
    }
    uint32_t outpk = (uint32_t)f2b(acc0) | ((uint32_t)f2b(acc1) << 16);
    *(uint32_t*)(samp + (size_t)pt * 128 + c2) = outpk;
}

// ================= 256-thread GEMM building blocks =================
__device__ __forceinline__ void stage_tile(const unsigned short* __restrict__ g, int ld,
                                           unsigned short* lds, int wave, int lane) {
    #pragma unroll
    for (int j = 0; j < 4; ++j) {
        int idx = wave * 256 + j * 64 + lane;      // chunk slot index 0..1023
        int r = idx >> 3;
        int cs = idx & 7;
        int cl = cs ^ (r & 7);                     // logical chunk this slot holds
        __builtin_amdgcn_global_load_lds(
            (const __attribute__((address_space(1))) void*)(g + (size_t)r * ld + cl * 8),
            (__attribute__((address_space(3))) void*)(lds + wave * 2048 + j * 512),
            16, 0, 0);
    }
}

__device__ __forceinline__ frag8 frag_read(const unsigned short* lds, int row, int chunk) {
    return *(const frag8*)(lds + row * 64 + ((chunk ^ (row & 7)) << 3));
}

__device__ __forceinline__ void mma_tile(const unsigned short* As, const unsigned short* Bs,
                                         int wm, int wn, int lane, f32x4 (&acc)[4][4]) {
    int lm = lane & 15, lq = lane >> 4;
    #pragma unroll
    for (int kk = 0; kk < 2; ++kk) {
        frag8 a[4], b[4];
        #pragma unroll
        for (int t = 0; t < 4; ++t) a[t] = frag_read(As, wm * 64 + t * 16 + lm, kk * 4 + lq);
        #pragma unroll
        for (int t = 0; t < 4; ++t) b[t] = frag_read(Bs, wn * 64 + t * 16 + lm, kk * 4 + lq);
        #pragma unroll
        for (int tm = 0; tm < 4; ++tm)
            #pragma unroll
            for (int tn = 0; tn < 4; ++tn)
                acc[tm][tn] = __builtin_amdgcn_mfma_f32_16x16x32_bf16(a[tm], b[tn], acc[tm][tn], 0, 0, 0);
    }
}

// ======== counted-vmcnt 2-deep pipeline (T4): loads stay in flight ACROSS barriers ========
template <int KT>
__device__ __forceinline__ void gemm_loop_pipe(const unsigned short* __restrict__ A, int ldA,
                                               const unsigned short* __restrict__ B, int ldB,
                                               unsigned short (*As)[BM * BK],
                                               unsigned short (*Bs)[BN * BK],
                                               int wave, int lane, int wm, int wn,
                                               f32x4 (&acc)[4][4]) {
    stage_tile(A, ldA, As[0], wave, lane);
    stage_tile(B, ldB, Bs[0], wave, lane);
    if (KT > 1) {
        stage_tile(A + BK, ldA, As[1], wave, lane);
        stage_tile(B + BK, ldB, Bs[1], wave, lane);
    }
    #pragma unroll
    for (int kt = 0; kt < KT; ++kt) {
        int cur = kt & 1;
        if (kt + 1 < KT) asm volatile("s_waitcnt vmcnt(8)" ::: "memory");
        else             asm volatile("s_waitcnt vmcnt(0)" ::: "memory");
        __builtin_amdgcn_s_barrier();              // buf[cur] ready for all waves
        mma_tile(As[cur], Bs[cur], wm, wn, lane, acc);
        asm volatile("s_waitcnt lgkmcnt(0)" ::: "memory");
        __builtin_amdgcn_s_barrier();              // all waves done reading buf[cur]
        if (kt + 2 < KT) {                         // refill buf[cur] for tile kt+2
            stage_tile(A + (kt + 2) * BK, ldA, As[cur], wave, lane);
            stage_tile(B + (kt + 2) * BK, ldB, Bs[cur], wave, lane);
        }
    }
}

// ---------------- H1 slice builder (cooperative, cvt_pk) ----------------
__device__ __forceinline__ void build_h1(const float* __restrict__ wls, float x, float y, float z,
                                         int r, int c0, int kt, unsigned short* __restrict__ As) {
    #pragma unroll
    for (int j = 0; j < 4; ++j) {
        int cl = c0 + j;
        const float* wp = wls + kt * 64 + cl * 8;      // wave-uniform -> LDS broadcast
        float4 a0l = *(const float4*)(wp),       a0h = *(const float4*)(wp + 4);
        float4 a1l = *(const float4*)(wp + 256), a1h = *(const float4*)(wp + 260);
        float4 a2l = *(const float4*)(wp + 512), a2h = *(const float4*)(wp + 516);
        float4 bbl = *(const float4*)(wp + 768), bbh = *(const float4*)(wp + 772);
        float v0 = fmaxf(x * a0l.x + y * a1l.x + z * a2l.x + bbl.x, 0.f);
        float v1 = fmaxf(x * a0l.y + y * a1l.y + z * a2l.y + bbl.y, 0.f);
        float v2 = fmaxf(x * a0l.z + y * a1l.z + z * a2l.z + bbl.z, 0.f);
        float v3 = fmaxf(x * a0l.w + y * a1l.w + z * a2l.w + bbl.w, 0.f);
        float v4 = fmaxf(x * a0h.x + y * a1h.x + z * a2h.x + bbh.x, 0.f);
        float v5 = fmaxf(x * a0h.y + y * a1h.y + z * a2h.y + bbh.y, 0.f);
        float v6 = fmaxf(x * a0h.z + y * a1h.z + z * a2h.z + bbh.z, 0.f);
        float v7 = fmaxf(x * a0h.w + y * a1h.w + z * a2h.w + bbh.w, 0.f);
        uint32_t q0 = cvtpk_bf16(v0, v1), q1 = cvtpk_bf16(v2, v3);
        uint32_t q2 = cvtpk_bf16(v4, v5), q3 = cvtpk_bf16(v6, v7);
        *(uint4*)(As + r * 64 + ((cl ^ (r & 7)) << 3)) = make_uint4(q0, q1, q2, q3);
    }
}

// ---------------- fused pe1+pe2, N=256 per block: H1 built ONCE per m0 ----------------
// grid 800. Was (800,2): both n0-blocks rebuilt the identical H1 tile (the VALU hot spot).
// Now one block owns all 256 output cols: acc[4][8], B tile = all 256 W2 rows (2x stage_tile,
// 8 loads/wave, build_h1 overlaps the load latency exactly as before).
__global__ __launch_bounds__(256) void k_pe12(const float* __restrict__ bev,
                                              const float* __restrict__ pw1,
                                              const float* __restrict__ pb1,
                                              const unsigned short* __restrict__ Bt,
                                              const float* __restrict__ bias,
                                              unsigned short* __restrict__ H2) {
    __shared__ unsigned short As[BM * BK];         // 16 KB
    __shared__ unsigned short Bs[256 * BK];        // 32 KB
    __shared__ __align__(16) float wls[4 * 256];   // rows 0..2 = w1, row 3 = b1 (4 KB)
    __shared__ float bevs[3 * 128];                // 1.5 KB
    int t = threadIdx.x, lane = t & 63, wave = t >> 6;
    int wm = wave >> 1, wn = wave & 1;
    int m0 = blockIdx.x * BM;
    {   // stage w1 (3x256) + b1 (256): 1024 floats, 4 per thread
        int i = t * 4;
        int j = i >> 8, c = i & 255;
        float4 v = (j < 3) ? *(const float4*)(pw1 + j * 256 + c)
                           : *(const float4*)(pb1 + c);
        *(float4*)(wls + i) = v;
    }
    if (t < 128) {   // this block's 128 bev rows (point index m = q*4+p, p inner)
        int m = m0 + t;
        int q = m >> 2, p = m & 3;
        int h = q / 160, w = q - h * 160;
        const float* bv = bev + ((size_t)((p * 160 + h) * 160 + w)) * 3;
        bevs[t] = bv[0]; bevs[128 + t] = bv[1]; bevs[256 + t] = bv[2];
    }
    __syncthreads();
    int r = t & 127;                      // this thread's H1 row
    int c0 = (t >> 7) * 4;                // first of its 4 chunks
    float x = bevs[r], y = bevs[128 + r], z = bevs[256 + r];
    int lm = lane & 15, lq = lane >> 4;
    f32x4 acc[4][8] = {};
    for (int kt = 0; kt < 4; ++kt) {
        stage_tile(Bt + kt * BK, 256, Bs, wave, lane);                    // W2 rows 0..127
        stage_tile(Bt + 128 * 256 + kt * BK, 256, Bs + 8192, wave, lane); // rows 128..255
        build_h1(wls, x, y, z, r, c0, kt, As);     // VALU+ds_write while loads fly
        __syncthreads();
        #pragma unroll
        for (int kk = 0; kk < 2; ++kk) {
            int ch = kk * 4 + lq;
            frag8 a[4], b[8];
            #pragma unroll
            for (int tt = 0; tt < 4; ++tt) a[tt] = frag_read(As, wm * 64 + tt * 16 + lm, ch);
            #pragma unroll
            for (int tn = 0; tn < 8; ++tn) {
                int brow = (tn < 4 ? wn * 64 + tn * 16 : 128 + wn * 64 + (tn - 4) * 16) + lm;
                b[tn] = frag_read(Bs, brow, ch);
            }
            #pragma unroll
            for (int tm = 0; tm < 4; ++tm)
                #pragma unroll
                for (int tn = 0; tn < 8; ++tn)
                    acc[tm][tn] = __builtin_amdgcn_mfma_f32_16x16x32_bf16(a[tm], b[tn], acc[tm][tn], 0, 0, 0);
        }
        __syncthreads();
    }
    #pragma unroll
    for (int tn = 0; tn < 8; ++tn) {
        int n = (tn < 4 ? wn * 64 + tn * 16 : 128 + wn * 64 + (tn - 4) * 16) + lm;
        float bn = bias[n];
        #pragma unroll
        for (int tm = 0; tm < 4; ++tm) {
            int mb = m0 + wm * 64 + tm * 16 + lq * 4;
            #pragma unroll
            for (int rr = 0; rr < 4; ++rr)
                H2[(size_t)(mb + rr) * 256 + n] = f2b(fmaxf(acc[tm][tn][rr] + bn, 0.f));
        }
    }
}

// ---------------- pe3: X = bf16(samp + H2 @ W3T^T + b3), counted-vmcnt pipeline ----------------
__global__ __launch_bounds__(256) void k_gemm_pe3(const unsigned short* __restrict__ A,
                                                  const unsigned short* __restrict__ Bt,
                                                  const float* __restrict__ bias,
                                                  const unsigned short* __restrict__ samp,
                                                  unsigned short* __restrict__ X) {
    __shared__ unsigned short As[2][BM * BK], Bs[2][BN * BK];
    int lane = threadIdx.x & 63, wave = threadIdx.x >> 6;
    int wm = wave >> 1, wn = wave & 1;
    int m0 = blockIdx.x * BM;
    f32x4 acc[4][4] = {};
    gemm_loop_pipe<4>(A + (size_t)m0 * 256, 256, Bt, 256, As, Bs, wave, lane, wm, wn, acc);
    int lm = lane & 15, lq = lane >> 4;
    #pragma unroll
    for (int tn = 0; tn < 4; ++tn) {
        int n = wn * 64 + tn * 16 + lm;
        float bn = bias[n];
        #pragma unroll
        for (int tm = 0; tm < 4; ++tm) {
            int mb = m0 + wm * 64 + tm * 16 + lq * 4;
            #pragma unroll
            for (int rr = 0; rr < 4; ++rr) {
                size_t off = (size_t)(mb + rr) * 128 + n;
                X[off] = f2b(acc[tm][tn][rr] + bn + b2f_bits(samp[off]));
            }
        }
    }
}

// ---------------- conv GEMM (counted-vmcnt pipeline) -> bf16 Y + optional stats ----------------
template <int K, bool STATS>
__global__ __launch_bounds__(256) void k_gemm_conv(const unsigned short* __restrict__ A,
                                                   const unsigned short* __restrict__ Bt,
                                                   const float* __restrict__ bias,
                                                   unsigned short* __restrict__ Y, int ldY,
                                                   float* __restrict__ st, int C) {
    __shared__ unsigned short As[2][BM * BK], Bs[2][BN * BK];
    int lane = threadIdx.x & 63, wave = threadIdx.x >> 6;
    int wm = wave >> 1, wn = wave & 1;
    int m0 = blockIdx.x * BM, n0 = blockIdx.y * BN;
    f32x4 acc[4][4] = {};
    gemm_loop_pipe<K / BK>(A + (size_t)m0 * K, K, Bt + (size_t)n0 * K, K,
                           As, Bs, wave, lane, wm, wn, acc);
    int lm = lane & 15, lq = lane >> 4;
    #pragma unroll
    for (int tn = 0; tn < 4; ++tn) {
        int n = n0 + wn * 64 + tn * 16 + lm;
        float bn = bias[n];
        float s1 = 0.f, s2 = 0.f;
        #pragma unroll
        for (int tm = 0; tm < 4; ++tm) {
            int mb = m0 + wm * 64 + tm * 16 + lq * 4;
            #pragma unroll
            for (int rr = 0; rr < 4; ++rr) {
                float v = acc[tm][tn][rr] + bn;
                Y[(size_t)(mb + rr) * ldY + n] = f2b(v);
                if (STATS) { s1 += v; s2 += v * v; }
            }
        }
        if (STATS) {
            s1 += __shfl_xor(s1, 16); s1 += __shfl_xor(s1, 32);
            s2 += __shfl_xor(s2, 16); s2 += __shfl_xor(s2, 32);
            if (lq == 0) { atomicAdd(&st[n], s1); atomicAdd(&st[C + n], s2); }
        }
    }
}

// ---------------- conv3 (counted-vmcnt pipeline) -> out f32 [128][25600] ----------------
__global__ __launch_bounds__(256) void k_gemm_conv3(const unsigned short* __restrict__ A,
                                                    const unsigned short* __restrict__ Bt,
                                                    const float* __restrict__ bias,
                                                    float* __restrict__ out) {
    __shared__ unsigned short As[2][BM * BK], Bs[2][BN * BK];
    int lane = threadIdx.x & 63, wave = threadIdx.x >> 6;
    int wm = wave >> 1, wn = wave & 1;
    int m0 = blockIdx.x * BM;
    f32x4 acc[4][4] = {};
    gemm_loop_pipe<2>(A + (size_t)m0 * 128, 128, Bt, 128, As, Bs, wave, lane, wm, wn, acc);
    int lm = lane & 15, lq = lane >> 4;
    #pragma unroll
    for (int tn = 0; tn < 4; ++tn) {
        int n = wn * 64 + tn * 16 + lm;
        float bn = bias[n];
        #pragma unroll
        for (int tm = 0; tm < 4; ++tm) {
            int mb = m0 + wm * 64 + tm * 16 + lq * 4;
            float4 pk;
            pk.x = acc[tm][tn][0] + bn;
            pk.y = acc[tm][tn][1] + bn;
            pk.z = acc[tm][tn][2] + bn;
            pk.w = acc[tm][tn][3] + bn;
            *(float4*)(out + (size_t)n * 25600 + mb) = pk;
        }
    }
}

// -------- norm+gelu with inline finalize (mean/rsqrt derived from raw sums) --------
__global__ void k_normgelu8f(const unsigned short* __restrict__ Y, const float* __restrict__ st,
                             unsigned short* __restrict__ X2, int Cmask, int C, float inv_n,
                             int total8) {
    int i8 = blockIdx.x * 256 + threadIdx.x;
    if (i8 >= total8) return;
    int e0 = i8 * 8;
    int c = e0 & Cmask;
    uint4 y = *(const uint4*)(Y + e0);
    float4 s1a = *(const float4*)(st + c);
    float4 s1b = *(const float4*)(st + c + 4);
    float4 s2a = *(const float4*)(st + C + c);
    float4 s2b = *(const float4*)(st + C + c + 4);
    float mu[8] = { s1a.x * inv_n, s1a.y * inv_n, s1a.z * inv_n, s1a.w * inv_n,
                    s1b.x * inv_n, s1b.y * inv_n, s1b.z * inv_n, s1b.w * inv_n };
    float sq[8] = { s2a.x, s2a.y, s2a.z, s2a.w, s2b.x, s2b.y, s2b.z, s2b.w };
    float rs[8];
    #pragma unroll
    for (int j = 0; j < 8; ++j) rs[j] = rsqrtf(sq[j] * inv_n - mu[j] * mu[j] + 1e-5f);
    const float is2 = 0.70710678118654752f;
    unsigned int yw[4] = {y.x, y.y, y.z, y.w};
    unsigned int ow[4];
    #pragma unroll
    for (int j = 0; j < 4; ++j) {
        float v0 = (b2f_bits((unsigned short)(yw[j] & 0xffffu)) - mu[j * 2]) * rs[j * 2];
        float v1 = (b2f_bits((unsigned short)(yw[j] >> 16)) - mu[j * 2 + 1]) * rs[j * 2 + 1];
        float g0 = 0.5f * v0 * (1.f + erff(v0 * is2));
        float g1 = 0.5f * v1 * (1.f + erff(v1 * is2));
        ow[j] = (uint32_t)f2b(g0) | ((uint32_t)f2b(g1) << 16);
    }
    *(uint4*)(X2 + e0) = make_uint4(ow[0], ow[1], ow[2], ow[3]);
}

// ---------------- launch ----------------
extern "C" void kernel_launch(void* const* d_in, const int* in_sizes, int n_in,
                              void* d_out, int out_size, void* d_ws, size_t ws_size,
                              hipStream_t stream) {
    (void)in_sizes; (void)n_in; (void)out_size; (void)ws_size;
    const float* feat = (const float*)d_in[0];
    const float* l2i  = (const float*)d_in[1];
    const float* bev  = (const float*)d_in[2];
    const float* pw1  = (const float*)d_in[3];
    const float* pb1  = (const float*)d_in[4];
    const float* pw2  = (const float*)d_in[5];
    const float* pb2  = (const float*)d_in[6];
    const float* pw3  = (const float*)d_in[7];
    const float* pb3  = (const float*)d_in[8];
    const float* c1w  = (const float*)d_in[9];
    const float* c1b  = (const float*)d_in[10];
    const float* c2w  = (const float*)d_in[11];
    const float* c2b  = (const float*)d_in[12];
    const float* c3w  = (const float*)d_in[13];
    const float* c3b  = (const float*)d_in[14];
    float* outp = (float*)d_out;
    char* ws = (char*)d_ws;

    // ---- workspace layout (bytes), peak ~148.6 MB ----
    unsigned short* featT = (unsigned short*)(ws + 0);          //  4,325,376 + 23,040 pad
    unsigned short* W2Tb  = (unsigned short*)(ws + 4348416);    //    131,072 [256][256] bf16 [o][k]
    unsigned short* W3Tb  = (unsigned short*)(ws + 4479488);    //     65,536 [128][256]
    unsigned short* C1Wb  = (unsigned short*)(ws + 4545024);    //    524,288 [512][512]
    unsigned short* C2Wb  = (unsigned short*)(ws + 5069312);    //    131,072 [128][512]
    unsigned short* C3Wb  = (unsigned short*)(ws + 5200384);    //     32,768 [128][128]
    float* stats          = (float*)(ws + 5233152);             //     10,240
    int*    poff          = (int*)(ws + 5247488);               //  2,457,600 [6][102400]
    float4* pwts          = (float4*)(ws + 7705088);            //  9,830,400 [6][102400]
    char* BUF1 = ws + 17535488;   // 52,428,800: X bf16 -> Y2 bf16 + X3 bf16
    char* BUF2 = ws + 69964288;   // 52,428,800: H2 bf16 -> Y1 bf16
    char* BUF3 = ws + 122393088;  // 26,214,400: samp bf16 -> X2 bf16

    float* st512 = stats;          // 1024 f (sums + sumsq)
    float* st128 = stats + 2048;   // 256 f

    unsigned short* H2   = (unsigned short*)BUF2;
    unsigned short* samp = (unsigned short*)BUF3;
    unsigned short* X    = (unsigned short*)BUF1;
    unsigned short* Y1   = (unsigned short*)BUF2;               // after H2 dead (conv1)
    unsigned short* X2   = (unsigned short*)BUF3;               // after samp dead (normgelu1)
    unsigned short* Y2   = (unsigned short*)BUF1;               // after X dead (conv2)
    unsigned short* X3   = (unsigned short*)(BUF1 + 6553600);

    // merged prep: projection + featT transpose + casts + stats zero
    k_prep<<<4393, 256, 0, stream>>>(feat, pw2, pw3, c1w, c2w, c3w, l2i, bev,
                                     featT, W2Tb, W3Tb, C1Wb, C2Wb, C3Wb, stats,
                                     poff, pwts);

    // gather-only sampling
    k_sample2<<<25600, 256, 0, stream>>>(featT, poff, pwts, samp);

    // PE MLP: fused pe1+pe2 (N=256 per block, H1 built once per m0), then pe3 (pipelined)
    k_pe12<<<800, 256, 0, stream>>>(bev, pw1, pb1, W2Tb, pb2, H2);
    k_gemm_pe3<<<dim3(800, 1), 256, 0, stream>>>(H2, W3Tb, pb3, samp, X);

    // conv1 (512->512, pipelined) + fused stats
    k_gemm_conv<512, true><<<dim3(200, 4), 256, 0, stream>>>(X, C1Wb, c1b, Y1, 512, st512, 512);
    k_normgelu8f<<<6400, 256, 0, stream>>>(Y1, st512, X2, 511, 512, 1.f / 25600.f, 1638400);

    // conv2 (512->128, pipelined, BN=128) + fused stats, then norm+gelu
    k_gemm_conv<512, true><<<dim3(200, 1), 256, 0, stream>>>(X2, C2Wb, c2b, Y2, 128, st128, 128);
    k_normgelu8f<<<1600, 256, 0, stream>>>(Y2, st128, X3, 127, 128, 1.f / 25600.f, 409600);

    // conv3 (128->128, pipelined) -> out f32 [128][25600]
    k_gemm_conv3<<<200, 256, 0, stream>>>(X3, C3Wb, c3b, outp);
}

// Round 8
// 268.636 us; speedup vs baseline: 1.0366x; 1.0366x over previous
//
#include <hip/hip_runtime.h>
#include <cstdint>
#include <cstddef>

using frag8 = __attribute__((ext_vector_type(8))) short;   // 8 bf16
using f32x4 = __attribute__((ext_vector_type(4))) float;

__device__ __forceinline__ float b2f_bits(unsigned short u) {
    union { uint32_t u32; float f; } x; x.u32 = ((uint32_t)u) << 16; return x.f;
}
__device__ __forceinline__ float b2f_lo(uint32_t pk) {
    return __builtin_bit_cast(float, pk << 16);
}
__device__ __forceinline__ float b2f_hi(uint32_t pk) {
    return __builtin_bit_cast(float, pk & 0xffff0000u);
}
__device__ __forceinline__ unsigned short f2b(float f) {   // RNE f32 -> bf16
    uint32_t u = __builtin_bit_cast(uint32_t, f);
    uint32_t r = (u + 0x7fffu + ((u >> 16) & 1u)) >> 16;
    return (unsigned short)r;
}
__device__ __forceinline__ uint32_t cvtpk_bf16(float lo, float hi) {   // RNE pack 2xf32->2xbf16
    uint32_t r;
    asm("v_cvt_pk_bf16_f32 %0, %1, %2" : "=v"(r) : "v"(lo), "v"(hi));
    return r;
}

#define HF 32
#define WFEAT 88
#define NCAM 6
#define NPT 102400
#define BM 128
#define BN 128
#define BK 64

// ================= merged prep: project + featT(LDS transpose) + casts + stats ========
__global__ __launch_bounds__(256) void k_prep(const float* __restrict__ feat,
                                              const float* __restrict__ pw2,
                                              const float* __restrict__ pw3,
                                              const float* __restrict__ c1w,
                                              const float* __restrict__ c2w,
                                              const float* __restrict__ c3w,
                                              const float* __restrict__ l2i,
                                              const float* __restrict__ bev,
                                              unsigned short* __restrict__ featT,
                                              unsigned short* __restrict__ W2Tb,
                                              unsigned short* __restrict__ W3Tb,
                                              unsigned short* __restrict__ C1Wb,
                                              unsigned short* __restrict__ C2Wb,
                                              unsigned short* __restrict__ C3Wb,
                                              float* __restrict__ stats,
                                              int* __restrict__ poff,
                                              float4* __restrict__ pwts) {
    __shared__ unsigned short tile[64 * 132];   // transpose tile (132 = 128 + pad)
    int b = blockIdx.x, t = threadIdx.x;
    if (b < 2400) {                       // ---- projection precompute (cam, point) ----
        int idx = b * 256 + t;            // n*NPT + pt, < 614400
        int n = idx / NPT, pt = idx - n * NPT;
        int q = pt >> 2, p = pt & 3;
        int h = q / 160, w = q - h * 160;
        const float* bv = bev + ((p * 160 + h) * 160 + w) * 3;
        float rx = bv[0] * 100.f - 50.f;
        float ry = bv[1] * 100.f - 50.f;
        float rz = bv[2] * 8.f - 4.f;
        const float* M = l2i + n * 16;
        float c0   = M[0] * rx + M[1] * ry + M[2]  * rz + M[3];
        float c1v  = M[4] * rx + M[5] * ry + M[6]  * rz + M[7];
        float homo = M[8] * rx + M[9] * ry + M[10] * rz + M[11];
        float z = fmaxf(homo, 1e-5f);
        float u = c0 / z / 704.0f;
        float v = c1v / z / 256.0f;
        if (!(homo > 1e-5f && u > 0.f && u < 1.f && v > 0.f && v < 1.f)) {
            poff[idx] = -1;
            return;
        }
        float fx = u * (float)WFEAT - 0.5f;
        float fy = v * (float)HF - 0.5f;
        float fx0 = floorf(fx), fy0 = floorf(fy);
        float dx = fx - fx0, dy = fy - fy0;
        int x0 = (int)fx0, y0 = (int)fy0;
        float wxa = (x0 < 0) ? dx : 1.f - dx;
        float wxb = (x0 >= 0 && x0 < WFEAT - 1) ? dx : 0.f;
        float wya = (y0 < 0) ? dy : 1.f - dy;
        float wyb = (y0 >= 0 && y0 < HF - 1) ? dy : 0.f;
        int bx = max(x0, 0), by = max(y0, 0);
        poff[idx] = ((n * HF + by) * WFEAT + bx) << 7;
        pwts[idx] = make_float4(wxa * wya, wxb * wya, wxa * wyb, wxb * wyb);
        return;
    }
    b -= 2400;
    if (b < 264) {                        // ---- feat -> featT via LDS tiled transpose ----
        int n = b / 44;
        int s0 = (b - n * 44) * 64;
        #pragma unroll
        for (int i = 0; i < 32; ++i) {
            int e = i * 256 + t;          // 8192 elems: c = e>>6, sl = e&63
            int c = e >> 6, sl = e & 63;
            tile[sl * 132 + c] = f2b(feat[(size_t)(n * 128 + c) * 2816 + s0 + sl]);
        }
        __syncthreads();
        #pragma unroll
        for (int j = 0; j < 8; ++j) {
            int flat = j * 1024 + t * 4;  // ushort4 chunks
            int sl = flat >> 7, c = flat & 127;
            ushort4 v = *(const ushort4*)(tile + sl * 132 + c);
            *(ushort4*)(featT + (size_t)(n * 2816 + s0 + sl) * 128 + c) = v;
        }
        return;
    }
    b -= 264;
    if (b < 256) {                        // ---- pw2 [256][256] -> W2Tb [o][k] ----
        int idx = b * 256 + t;
        int r = idx >> 8, c = idx & 255;
        W2Tb[c * 256 + r] = f2b(pw2[idx]);
        return;
    }
    b -= 256;
    if (b < 128) {                        // ---- pw3 [256][128] -> W3Tb [o][k] ----
        int idx = b * 256 + t;
        int r = idx >> 7, c = idx & 127;
        W3Tb[c * 256 + r] = f2b(pw3[idx]);
        return;
    }
    b -= 128;
    if (b < 1024) { int idx = b * 256 + t; C1Wb[idx] = f2b(c1w[idx]); return; }
    b -= 1024;
    if (b < 256)  { int idx = b * 256 + t; C2Wb[idx] = f2b(c2w[idx]); return; }
    b -= 256;
    if (b < 64)   { int idx = b * 256 + t; C3Wb[idx] = f2b(c3w[idx]); return; }
    // ---- stats zero (2560 floats: st512 @0, st128 @2048) ----
    #pragma unroll
    for (int j = 0; j < 10; ++j) stats[t * 10 + j] = 0.f;
}

// ---------------- gather-only sampling: one wave per point, lane = 2 channels ----------------
__global__ __launch_bounds__(256) void k_sample2(const unsigned short* __restrict__ featT,
                                                 const int* __restrict__ poff,
                                                 const float4* __restrict__ pwts,
                                                 unsigned short* __restrict__ samp) {
    int pt = blockIdx.x * 4 + (threadIdx.x >> 6);
    int lane = threadIdx.x & 63;
    int c2 = lane * 2;
    int offs[NCAM];
    float4 ww[NCAM];
    #pragma unroll
    for (int n = 0; n < NCAM; ++n) offs[n] = poff[n * NPT + pt];
    #pragma unroll
    for (int n = 0; n < NCAM; ++n) ww[n] = pwts[n * NPT + pt];   // garbage if invalid; unused
    float acc0 = 0.f, acc1 = 0.f;
    #pragma unroll
    for (int n = 0; n < NCAM; ++n) {
        if (offs[n] >= 0) {                        // wave-uniform scalar branch
            const unsigned short* base = featT + offs[n] + c2;
            uint32_t p00 = *(const uint32_t*)(base);
            uint32_t p01 = *(const uint32_t*)(base + 128);
            uint32_t p10 = *(const uint32_t*)(base + WFEAT * 128);
            uint32_t p11 = *(const uint32_t*)(base + WFEAT * 128 + 128);
            float4 w = ww[n];
            acc0 += w.x * b2f_lo(p00) + w.y * b2f_lo(p01) + w.z * b2f_lo(p10) + w.w * b2f_lo(p11);
            acc1 += w.x * b2f_hi(p00) + w.y * b2f_hi(p01) + w.z * b2f_hi(p10) + w.w * b2f_hi(p11);
        }
    }
    uint32_t outpk = (uint32_t)f2b(acc0) | ((uint32_t)f2b(acc1) << 16);
    *(uint32_t*)(samp + (size_t)pt * 128 + c2) = outpk;
}

// ================= 256-thread GEMM building blocks =================
__device__ __forceinline__ void stage_tile(const unsigned short* __restrict__ g, int ld,
                                           unsigned short* lds, int wave, int lane) {
    #pragma unroll
    for (int j = 0; j < 4; ++j) {
        int idx = wave * 256 + j * 64 + lane;      // chunk slot index 0..1023
        int r = idx >> 3;
        int cs = idx & 7;
        int cl = cs ^ (r & 7);                     // logical chunk this slot holds
        __builtin_amdgcn_global_load_lds(
            (const __attribute__((address_space(1))) void*)(g + (size_t)r * ld + cl * 8),
            (__attribute__((address_space(3))) void*)(lds + wave * 2048 + j * 512),
            16, 0, 0);
    }
}

__device__ __forceinline__ frag8 frag_read(const unsigned short* lds, int row, int chunk) {
    return *(const frag8*)(lds + row * 64 + ((chunk ^ (row & 7)) << 3));
}

__device__ __forceinline__ void mma_tile(const unsigned short* As, const unsigned short* Bs,
                                         int wm, int wn, int lane, f32x4 (&acc)[4][4]) {
    int lm = lane & 15, lq = lane >> 4;
    #pragma unroll
    for (int kk = 0; kk < 2; ++kk) {
        frag8 a[4], b[4];
        #pragma unroll
        for (int t = 0; t < 4; ++t) a[t] = frag_read(As, wm * 64 + t * 16 + lm, kk * 4 + lq);
        #pragma unroll
        for (int t = 0; t < 4; ++t) b[t] = frag_read(Bs, wn * 64 + t * 16 + lm, kk * 4 + lq);
        #pragma unroll
        for (int tm = 0; tm < 4; ++tm)
            #pragma unroll
            for (int tn = 0; tn < 4; ++tn)
                acc[tm][tn] = __builtin_amdgcn_mfma_f32_16x16x32_bf16(a[tm], b[tn], acc[tm][tn], 0, 0, 0);
    }
}

// ======== counted-vmcnt 2-deep pipeline (T4): loads stay in flight ACROSS barriers ========
template <int KT>
__device__ __forceinline__ void gemm_loop_pipe(const unsigned short* __restrict__ A, int ldA,
                                               const unsigned short* __restrict__ B, int ldB,
                                               unsigned short (*As)[BM * BK],
                                               unsigned short (*Bs)[BN * BK],
                                               int wave, int lane, int wm, int wn,
                                               f32x4 (&acc)[4][4]) {
    stage_tile(A, ldA, As[0], wave, lane);
    stage_tile(B, ldB, Bs[0], wave, lane);
    if (KT > 1) {
        stage_tile(A + BK, ldA, As[1], wave, lane);
        stage_tile(B + BK, ldB, Bs[1], wave, lane);
    }
    #pragma unroll
    for (int kt = 0; kt < KT; ++kt) {
        int cur = kt & 1;
        if (kt + 1 < KT) asm volatile("s_waitcnt vmcnt(8)" ::: "memory");
        else             asm volatile("s_waitcnt vmcnt(0)" ::: "memory");
        __builtin_amdgcn_s_barrier();              // buf[cur] ready for all waves
        mma_tile(As[cur], Bs[cur], wm, wn, lane, acc);
        asm volatile("s_waitcnt lgkmcnt(0)" ::: "memory");
        __builtin_amdgcn_s_barrier();              // all waves done reading buf[cur]
        if (kt + 2 < KT) {                         // refill buf[cur] for tile kt+2
            stage_tile(A + (kt + 2) * BK, ldA, As[cur], wave, lane);
            stage_tile(B + (kt + 2) * BK, ldB, Bs[cur], wave, lane);
        }
    }
}

// ---------------- H1 slice builder (cooperative, cvt_pk) — 2 chunks/thread ----------------
__device__ __forceinline__ void build_h1_2(const float* __restrict__ wls, float x, float y, float z,
                                           int r, int c0, int kt, unsigned short* __restrict__ As) {
    #pragma unroll
    for (int j = 0; j < 2; ++j) {
        int cl = c0 + j;
        const float* wp = wls + kt * 64 + cl * 8;      // wave-uniform -> LDS broadcast
        float4 a0l = *(const float4*)(wp),       a0h = *(const float4*)(wp + 4);
        float4 a1l = *(const float4*)(wp + 256), a1h = *(const float4*)(wp + 260);
        float4 a2l = *(const float4*)(wp + 512), a2h = *(const float4*)(wp + 516);
        float4 bbl = *(const float4*)(wp + 768), bbh = *(const float4*)(wp + 772);
        float v0 = fmaxf(x * a0l.x + y * a1l.x + z * a2l.x + bbl.x, 0.f);
        float v1 = fmaxf(x * a0l.y + y * a1l.y + z * a2l.y + bbl.y, 0.f);
        float v2 = fmaxf(x * a0l.z + y * a1l.z + z * a2l.z + bbl.z, 0.f);
        float v3 = fmaxf(x * a0l.w + y * a1l.w + z * a2l.w + bbl.w, 0.f);
        float v4 = fmaxf(x * a0h.x + y * a1h.x + z * a2h.x + bbh.x, 0.f);
        float v5 = fmaxf(x * a0h.y + y * a1h.y + z * a2h.y + bbh.y, 0.f);
        float v6 = fmaxf(x * a0h.z + y * a1h.z + z * a2h.z + bbh.z, 0.f);
        float v7 = fmaxf(x * a0h.w + y * a1h.w + z * a2h.w + bbh.w, 0.f);
        uint32_t q0 = cvtpk_bf16(v0, v1), q1 = cvtpk_bf16(v2, v3);
        uint32_t q2 = cvtpk_bf16(v4, v5), q3 = cvtpk_bf16(v6, v7);
        *(uint4*)(As + r * 64 + ((cl ^ (r & 7)) << 3)) = make_uint4(q0, q1, q2, q3);
    }
}

// ---------------- fused pe1+pe2, BM=64 x BN=256, grid 1600: H1 built ONCE, acc stays [4][4] ----------------
// R6 lesson: N-fat acc[4][8] (164 VGPR, 54.8KB LDS) killed occupancy. This shape halves the
// per-thread H1 build vs R5 (64 elems, no duplication) while keeping VGPR ~R5-level:
// waves split N four ways (wave w owns cols w*64..+63); A-rows 0..63 shared.
__global__ __launch_bounds__(256) void k_pe12(const float* __restrict__ bev,
                                              const float* __restrict__ pw1,
                                              const float* __restrict__ pb1,
                                              const unsigned short* __restrict__ Bt,
                                              const float* __restrict__ bias,
                                              unsigned short* __restrict__ H2) {
    __shared__ unsigned short As[64 * BK];         // 8 KB
    __shared__ unsigned short Bs[256 * BK];        // 32 KB
    __shared__ __align__(16) float wls[4 * 256];   // rows 0..2 = w1, row 3 = b1 (4 KB)
    __shared__ float bevs[3 * 64];                 // 0.75 KB
    int t = threadIdx.x, lane = t & 63, wave = t >> 6;
    int m0 = blockIdx.x * 64;
    {   // stage w1 (3x256) + b1 (256): 1024 floats, 4 per thread
        int i = t * 4;
        int j = i >> 8, c = i & 255;
        float4 v = (j < 3) ? *(const float4*)(pw1 + j * 256 + c)
                           : *(const float4*)(pb1 + c);
        *(float4*)(wls + i) = v;
    }
    if (t < 64) {    // this block's 64 bev rows (point index m = q*4+p, p inner)
        int m = m0 + t;
        int q = m >> 2, p = m & 3;
        int h = q / 160, w = q - h * 160;
        const float* bv = bev + ((size_t)((p * 160 + h) * 160 + w)) * 3;
        bevs[t] = bv[0]; bevs[64 + t] = bv[1]; bevs[128 + t] = bv[2];
    }
    __syncthreads();
    int r = t & 63;                       // this thread's H1 row
    int c0 = (t >> 6) * 2;                // first of its 2 chunks
    float x = bevs[r], y = bevs[64 + r], z = bevs[128 + r];
    int lm = lane & 15, lq = lane >> 4;
    f32x4 acc[4][4] = {};
    for (int kt = 0; kt < 4; ++kt) {
        stage_tile(Bt + kt * BK, 256, Bs, wave, lane);                    // W2 rows 0..127
        stage_tile(Bt + 128 * 256 + kt * BK, 256, Bs + 8192, wave, lane); // rows 128..255
        build_h1_2(wls, x, y, z, r, c0, kt, As);   // VALU+ds_write while loads fly
        __syncthreads();
        #pragma unroll
        for (int kk = 0; kk < 2; ++kk) {
            int ch = kk * 4 + lq;
            frag8 a[4], b[4];
            #pragma unroll
            for (int tt = 0; tt < 4; ++tt) a[tt] = frag_read(As, tt * 16 + lm, ch);
            #pragma unroll
            for (int tn = 0; tn < 4; ++tn) b[tn] = frag_read(Bs, wave * 64 + tn * 16 + lm, ch);
            #pragma unroll
            for (int tm = 0; tm < 4; ++tm)
                #pragma unroll
                for (int tn = 0; tn < 4; ++tn)
                    acc[tm][tn] = __builtin_amdgcn_mfma_f32_16x16x32_bf16(a[tm], b[tn], acc[tm][tn], 0, 0, 0);
        }
        __syncthreads();
    }
    #pragma unroll
    for (int tn = 0; tn < 4; ++tn) {
        int n = wave * 64 + tn * 16 + lm;
        float bn = bias[n];
        #pragma unroll
        for (int tm = 0; tm < 4; ++tm) {
            int mb = m0 + tm * 16 + lq * 4;
            #pragma unroll
            for (int rr = 0; rr < 4; ++rr)
                H2[(size_t)(mb + rr) * 256 + n] = f2b(fmaxf(acc[tm][tn][rr] + bn, 0.f));
        }
    }
}

// ---------------- pe3: X = bf16(samp + H2 @ W3T^T + b3), counted-vmcnt pipeline ----------------
__global__ __launch_bounds__(256) void k_gemm_pe3(const unsigned short* __restrict__ A,
                                                  const unsigned short* __restrict__ Bt,
                                                  const float* __restrict__ bias,
                                                  const unsigned short* __restrict__ samp,
                                                  unsigned short* __restrict__ X) {
    __shared__ unsigned short As[2][BM * BK], Bs[2][BN * BK];
    int lane = threadIdx.x & 63, wave = threadIdx.x >> 6;
    int wm = wave >> 1, wn = wave & 1;
    int m0 = blockIdx.x * BM;
    f32x4 acc[4][4] = {};
    gemm_loop_pipe<4>(A + (size_t)m0 * 256, 256, Bt, 256, As, Bs, wave, lane, wm, wn, acc);
    int lm = lane & 15, lq = lane >> 4;
    #pragma unroll
    for (int tn = 0; tn < 4; ++tn) {
        int n = wn * 64 + tn * 16 + lm;
        float bn = bias[n];
        #pragma unroll
        for (int tm = 0; tm < 4; ++tm) {
            int mb = m0 + wm * 64 + tm * 16 + lq * 4;
            #pragma unroll
            for (int rr = 0; rr < 4; ++rr) {
                size_t off = (size_t)(mb + rr) * 128 + n;
                X[off] = f2b(acc[tm][tn][rr] + bn + b2f_bits(samp[off]));
            }
        }
    }
}

// ---------------- conv GEMM (counted-vmcnt pipeline) -> bf16 Y + optional stats ----------------
template <int K, bool STATS>
__global__ __launch_bounds__(256) void k_gemm_conv(const unsigned short* __restrict__ A,
                                                   const unsigned short* __restrict__ Bt,
                                                   const float* __restrict__ bias,
                                                   unsigned short* __restrict__ Y, int ldY,
                                                   float* __restrict__ st, int C) {
    __shared__ unsigned short As[2][BM * BK], Bs[2][BN * BK];
    int lane = threadIdx.x & 63, wave = threadIdx.x >> 6;
    int wm = wave >> 1, wn = wave & 1;
    int m0 = blockIdx.x * BM, n0 = blockIdx.y * BN;
    f32x4 acc[4][4] = {};
    gemm_loop_pipe<K / BK>(A + (size_t)m0 * K, K, Bt + (size_t)n0 * K, K,
                           As, Bs, wave, lane, wm, wn, acc);
    int lm = lane & 15, lq = lane >> 4;
    #pragma unroll
    for (int tn = 0; tn < 4; ++tn) {
        int n = n0 + wn * 64 + tn * 16 + lm;
        float bn = bias[n];
        float s1 = 0.f, s2 = 0.f;
        #pragma unroll
        for (int tm = 0; tm < 4; ++tm) {
            int mb = m0 + wm * 64 + tm * 16 + lq * 4;
            #pragma unroll
            for (int rr = 0; rr < 4; ++rr) {
                float v = acc[tm][tn][rr] + bn;
                Y[(size_t)(mb + rr) * ldY + n] = f2b(v);
                if (STATS) { s1 += v; s2 += v * v; }
            }
        }
        if (STATS) {
            s1 += __shfl_xor(s1, 16); s1 += __shfl_xor(s1, 32);
            s2 += __shfl_xor(s2, 16); s2 += __shfl_xor(s2, 32);
            if (lq == 0) { atomicAdd(&st[n], s1); atomicAdd(&st[C + n], s2); }
        }
    }
}

// ---------------- conv3 (counted-vmcnt pipeline) -> out f32 [128][25600] ----------------
__global__ __launch_bounds__(256) void k_gemm_conv3(const unsigned short* __restrict__ A,
                                                    const unsigned short* __restrict__ Bt,
                                                    const float* __restrict__ bias,
                                                    float* __restrict__ out) {
    __shared__ unsigned short As[2][BM * BK], Bs[2][BN * BK];
    int lane = threadIdx.x & 63, wave = threadIdx.x >> 6;
    int wm = wave >> 1, wn = wave & 1;
    int m0 = blockIdx.x * BM;
    f32x4 acc[4][4] = {};
    gemm_loop_pipe<2>(A + (size_t)m0 * 128, 128, Bt, 128, As, Bs, wave, lane, wm, wn, acc);
    int lm = lane & 15, lq = lane >> 4;
    #pragma unroll
    for (int tn = 0; tn < 4; ++tn) {
        int n = wn * 64 + tn * 16 + lm;
        float bn = bias[n];
        #pragma unroll
        for (int tm = 0; tm < 4; ++tm) {
            int mb = m0 + wm * 64 + tm * 16 + lq * 4;
            float4 pk;
            pk.x = acc[tm][tn][0] + bn;
            pk.y = acc[tm][tn][1] + bn;
            pk.z = acc[tm][tn][2] + bn;
            pk.w = acc[tm][tn][3] + bn;
            *(float4*)(out + (size_t)n * 25600 + mb) = pk;
        }
    }
}

// -------- norm+gelu with inline finalize (mean/rsqrt derived from raw sums) --------
__global__ void k_normgelu8f(const unsigned short* __restrict__ Y, const float* __restrict__ st,
                             unsigned short* __restrict__ X2, int Cmask, int C, float inv_n,
                             int total8) {
    int i8 = blockIdx.x * 256 + threadIdx.x;
    if (i8 >= total8) return;
    int e0 = i8 * 8;
    int c = e0 & Cmask;
    uint4 y = *(const uint4*)(Y + e0);
    float4 s1a = *(const float4*)(st + c);
    float4 s1b = *(const float4*)(st + c + 4);
    float4 s2a = *(const float4*)(st + C + c);
    float4 s2b = *(const float4*)(st + C + c + 4);
    float mu[8] = { s1a.x * inv_n, s1a.y * inv_n, s1a.z * inv_n, s1a.w * inv_n,
                    s1b.x * inv_n, s1b.y * inv_n, s1b.z * inv_n, s1b.w * inv_n };
    float sq[8] = { s2a.x, s2a.y, s2a.z, s2a.w, s2b.x, s2b.y, s2b.z, s2b.w };
    float rs[8];
    #pragma unroll
    for (int j = 0; j < 8; ++j) rs[j] = rsqrtf(sq[j] * inv_n - mu[j] * mu[j] + 1e-5f);
    const float is2 = 0.70710678118654752f;
    unsigned int yw[4] = {y.x, y.y, y.z, y.w};
    unsigned int ow[4];
    #pragma unroll
    for (int j = 0; j < 4; ++j) {
        float v0 = (b2f_bits((unsigned short)(yw[j] & 0xffffu)) - mu[j * 2]) * rs[j * 2];
        float v1 = (b2f_bits((unsigned short)(yw[j] >> 16)) - mu[j * 2 + 1]) * rs[j * 2 + 1];
        float g0 = 0.5f * v0 * (1.f + erff(v0 * is2));
        float g1 = 0.5f * v1 * (1.f + erff(v1 * is2));
        ow[j] = (uint32_t)f2b(g0) | ((uint32_t)f2b(g1) << 16);
    }
    *(uint4*)(X2 + e0) = make_uint4(ow[0], ow[1], ow[2], ow[3]);
}

// ---------------- launch ----------------
extern "C" void kernel_launch(void* const* d_in, const int* in_sizes, int n_in,
                              void* d_out, int out_size, void* d_ws, size_t ws_size,
                              hipStream_t stream) {
    (void)in_sizes; (void)n_in; (void)out_size; (void)ws_size;
    const float* feat = (const float*)d_in[0];
    const float* l2i  = (const float*)d_in[1];
    const float* bev  = (const float*)d_in[2];
    const float* pw1  = (const float*)d_in[3];
    const float* pb1  = (const float*)d_in[4];
    const float* pw2  = (const float*)d_in[5];
    const float* pb2  = (const float*)d_in[6];
    const float* pw3  = (const float*)d_in[7];
    const float* pb3  = (const float*)d_in[8];
    const float* c1w  = (const float*)d_in[9];
    const float* c1b  = (const float*)d_in[10];
    const float* c2w  = (const float*)d_in[11];
    const float* c2b  = (const float*)d_in[12];
    const float* c3w  = (const float*)d_in[13];
    const float* c3b  = (const float*)d_in[14];
    float* outp = (float*)d_out;
    char* ws = (char*)d_ws;

    // ---- workspace layout (bytes), peak ~148.6 MB ----
    unsigned short* featT = (unsigned short*)(ws + 0);          //  4,325,376 + 23,040 pad
    unsigned short* W2Tb  = (unsigned short*)(ws + 4348416);    //    131,072 [256][256] bf16 [o][k]
    unsigned short* W3Tb  = (unsigned short*)(ws + 4479488);    //     65,536 [128][256]
    unsigned short* C1Wb  = (unsigned short*)(ws + 4545024);    //    524,288 [512][512]
    unsigned short* C2Wb  = (unsigned short*)(ws + 5069312);    //    131,072 [128][512]
    unsigned short* C3Wb  = (unsigned short*)(ws + 5200384);    //     32,768 [128][128]
    float* stats          = (float*)(ws + 5233152);             //     10,240
    int*    poff          = (int*)(ws + 5247488);               //  2,457,600 [6][102400]
    float4* pwts          = (float4*)(ws + 7705088);            //  9,830,400 [6][102400]
    char* BUF1 = ws + 17535488;   // 52,428,800: X bf16 -> Y2 bf16 + X3 bf16
    char* BUF2 = ws + 69964288;   // 52,428,800: H2 bf16 -> Y1 bf16
    char* BUF3 = ws + 122393088;  // 26,214,400: samp bf16 -> X2 bf16

    float* st512 = stats;          // 1024 f (sums + sumsq)
    float* st128 = stats + 2048;   // 256 f

    unsigned short* H2   = (unsigned short*)BUF2;
    unsigned short* samp = (unsigned short*)BUF3;
    unsigned short* X    = (unsigned short*)BUF1;
    unsigned short* Y1   = (unsigned short*)BUF2;               // after H2 dead (conv1)
    unsigned short* X2   = (unsigned short*)BUF3;               // after samp dead (normgelu1)
    unsigned short* Y2   = (unsigned short*)BUF1;               // after X dead (conv2)
    unsigned short* X3   = (unsigned short*)(BUF1 + 6553600);

    // merged prep: projection + featT transpose + casts + stats zero
    k_prep<<<4393, 256, 0, stream>>>(feat, pw2, pw3, c1w, c2w, c3w, l2i, bev,
                                     featT, W2Tb, W3Tb, C1Wb, C2Wb, C3Wb, stats,
                                     poff, pwts);

    // gather-only sampling
    k_sample2<<<25600, 256, 0, stream>>>(featT, poff, pwts, samp);

    // PE MLP: fused pe1+pe2 (BM=64 x BN=256, H1 built once, grid 1600), then pe3 (pipelined)
    k_pe12<<<1600, 256, 0, stream>>>(bev, pw1, pb1, W2Tb, pb2, H2);
    k_gemm_pe3<<<dim3(800, 1), 256, 0, stream>>>(H2, W3Tb, pb3, samp, X);

    // conv1 (512->512, pipelined) + fused stats
    k_gemm_conv<512, true><<<dim3(200, 4), 256, 0, stream>>>(X, C1Wb, c1b, Y1, 512, st512, 512);
    k_normgelu8f<<<6400, 256, 0, stream>>>(Y1, st512, X2, 511, 512, 1.f / 25600.f, 1638400);

    // conv2 (512->128, pipelined, BN=128) + fused stats, then norm+gelu
    k_gemm_conv<512, true><<<dim3(200, 1), 256, 0, stream>>>(X2, C2Wb, c2b, Y2, 128, st128, 128);
    k_normgelu8f<<<1600, 256, 0, stream>>>(Y2, st128, X3, 127, 128, 1.f / 25600.f, 409600);

    // conv3 (128->128, pipelined) -> out f32 [128][25600]
    k_gemm_conv3<<<200, 256, 0, stream>>>(X3, C3Wb, c3b, outp);
}

// Round 9
// 263.026 us; speedup vs baseline: 1.0587x; 1.0213x over previous
//
#include <hip/hip_runtime.h>
#include <cstdint>
#include <cstddef>

using frag8 = __attribute__((ext_vector_type(8))) short;   // 8 bf16
using f32x4 = __attribute__((ext_vector_type(4))) float;

__device__ __forceinline__ float b2f_bits(unsigned short u) {
    union { uint32_t u32; float f; } x; x.u32 = ((uint32_t)u) << 16; return x.f;
}
__device__ __forceinline__ float b2f_lo(uint32_t pk) {
    return __builtin_bit_cast(float, pk << 16);
}
__device__ __forceinline__ float b2f_hi(uint32_t pk) {
    return __builtin_bit_cast(float, pk & 0xffff0000u);
}
__device__ __forceinline__ unsigned short f2b(float f) {   // RNE f32 -> bf16
    uint32_t u = __builtin_bit_cast(uint32_t, f);
    uint32_t r = (u + 0x7fffu + ((u >> 16) & 1u)) >> 16;
    return (unsigned short)r;
}
__device__ __forceinline__ uint32_t cvtpk_bf16(float lo, float hi) {   // RNE pack 2xf32->2xbf16
    uint32_t r;
    asm("v_cvt_pk_bf16_f32 %0, %1, %2" : "=v"(r) : "v"(lo), "v"(hi));
    return r;
}

#define HF 32
#define WFEAT 88
#define NCAM 6
#define NPT 102400
#define BM 128
#define BN 128
#define BK 64

// ================= merged prep: project + featT(LDS transpose) + casts + stats ========
__global__ __launch_bounds__(256) void k_prep(const float* __restrict__ feat,
                                              const float* __restrict__ pw2,
                                              const float* __restrict__ pw3,
                                              const float* __restrict__ c1w,
                                              const float* __restrict__ c2w,
                                              const float* __restrict__ c3w,
                                              const float* __restrict__ l2i,
                                              const float* __restrict__ bev,
                                              unsigned short* __restrict__ featT,
                                              unsigned short* __restrict__ W2Tb,
                                              unsigned short* __restrict__ W3Tb,
                                              unsigned short* __restrict__ C1Wb,
                                              unsigned short* __restrict__ C2Wb,
                                              unsigned short* __restrict__ C3Wb,
                                              float* __restrict__ stats,
                                              int* __restrict__ poff,
                                              float4* __restrict__ pwts) {
    __shared__ unsigned short tile[64 * 132];   // transpose tile (132 = 128 + pad)
    int b = blockIdx.x, t = threadIdx.x;
    if (b < 2400) {                       // ---- projection precompute (cam, point) ----
        int idx = b * 256 + t;            // n*NPT + pt, < 614400
        int n = idx / NPT, pt = idx - n * NPT;
        int q = pt >> 2, p = pt & 3;
        int h = q / 160, w = q - h * 160;
        const float* bv = bev + ((p * 160 + h) * 160 + w) * 3;
        float rx = bv[0] * 100.f - 50.f;
        float ry = bv[1] * 100.f - 50.f;
        float rz = bv[2] * 8.f - 4.f;
        const float* M = l2i + n * 16;
        float c0   = M[0] * rx + M[1] * ry + M[2]  * rz + M[3];
        float c1v  = M[4] * rx + M[5] * ry + M[6]  * rz + M[7];
        float homo = M[8] * rx + M[9] * ry + M[10] * rz + M[11];
        float z = fmaxf(homo, 1e-5f);
        float u = c0 / z / 704.0f;
        float v = c1v / z / 256.0f;
        if (!(homo > 1e-5f && u > 0.f && u < 1.f && v > 0.f && v < 1.f)) {
            poff[idx] = -1;
            return;
        }
        float fx = u * (float)WFEAT - 0.5f;
        float fy = v * (float)HF - 0.5f;
        float fx0 = floorf(fx), fy0 = floorf(fy);
        float dx = fx - fx0, dy = fy - fy0;
        int x0 = (int)fx0, y0 = (int)fy0;
        float wxa = (x0 < 0) ? dx : 1.f - dx;
        float wxb = (x0 >= 0 && x0 < WFEAT - 1) ? dx : 0.f;
        float wya = (y0 < 0) ? dy : 1.f - dy;
        float wyb = (y0 >= 0 && y0 < HF - 1) ? dy : 0.f;
        int bx = max(x0, 0), by = max(y0, 0);
        poff[idx] = ((n * HF + by) * WFEAT + bx) << 7;
        pwts[idx] = make_float4(wxa * wya, wxb * wya, wxa * wyb, wxb * wyb);
        return;
    }
    b -= 2400;
    if (b < 264) {                        // ---- feat -> featT via LDS tiled transpose ----
        int n = b / 44;
        int s0 = (b - n * 44) * 64;
        #pragma unroll
        for (int i = 0; i < 32; ++i) {
            int e = i * 256 + t;          // 8192 elems: c = e>>6, sl = e&63
            int c = e >> 6, sl = e & 63;
            tile[sl * 132 + c] = f2b(feat[(size_t)(n * 128 + c) * 2816 + s0 + sl]);
        }
        __syncthreads();
        #pragma unroll
        for (int j = 0; j < 8; ++j) {
            int flat = j * 1024 + t * 4;  // ushort4 chunks
            int sl = flat >> 7, c = flat & 127;
            ushort4 v = *(const ushort4*)(tile + sl * 132 + c);
            *(ushort4*)(featT + (size_t)(n * 2816 + s0 + sl) * 128 + c) = v;
        }
        return;
    }
    b -= 264;
    if (b < 256) {                        // ---- pw2 [256][256] -> W2Tb [o][k] ----
        int idx = b * 256 + t;
        int r = idx >> 8, c = idx & 255;
        W2Tb[c * 256 + r] = f2b(pw2[idx]);
        return;
    }
    b -= 256;
    if (b < 128) {                        // ---- pw3 [256][128] -> W3Tb [o][k] ----
        int idx = b * 256 + t;
        int r = idx >> 7, c = idx & 127;
        W3Tb[c * 256 + r] = f2b(pw3[idx]);
        return;
    }
    b -= 128;
    if (b < 1024) { int idx = b * 256 + t; C1Wb[idx] = f2b(c1w[idx]); return; }
    b -= 1024;
    if (b < 256)  { int idx = b * 256 + t; C2Wb[idx] = f2b(c2w[idx]); return; }
    b -= 256;
    if (b < 64)   { int idx = b * 256 + t; C3Wb[idx] = f2b(c3w[idx]); return; }
    // ---- stats zero (2560 floats: st512 @0, st128 @2048) ----
    #pragma unroll
    for (int j = 0; j < 10; ++j) stats[t * 10 + j] = 0.f;
}

// ---------------- gather-only sampling: one wave per point, lane = 2 channels ----------------
__global__ __launch_bounds__(256) void k_sample2(const unsigned short* __restrict__ featT,
                                                 const int* __restrict__ poff,
                                                 const float4* __restrict__ pwts,
                                                 unsigned short* __restrict__ samp) {
    int pt = blockIdx.x * 4 + (threadIdx.x >> 6);
    int lane = threadIdx.x & 63;
    int c2 = lane * 2;
    int offs[NCAM];
    float4 ww[NCAM];
    #pragma unroll
    for (int n = 0; n < NCAM; ++n) offs[n] = poff[n * NPT + pt];
    #pragma unroll
    for (int n = 0; n < NCAM; ++n) ww[n] = pwts[n * NPT + pt];   // garbage if invalid; unused
    float acc0 = 0.f, acc1 = 0.f;
    #pragma unroll
    for (int n = 0; n < NCAM; ++n) {
        if (offs[n] >= 0) {                        // wave-uniform scalar branch
            const unsigned short* base = featT + offs[n] + c2;
            uint32_t p00 = *(const uint32_t*)(base);
            uint32_t p01 = *(const uint32_t*)(base + 128);
            uint32_t p10 = *(const uint32_t*)(base + WFEAT * 128);
            uint32_t p11 = *(const uint32_t*)(base + WFEAT * 128 + 128);
            float4 w = ww[n];
            acc0 += w.x * b2f_lo(p00) + w.y * b2f_lo(p01) + w.z * b2f_lo(p10) + w.w * b2f_lo(p11);
            acc1 += w.x * b2f_hi(p00) + w.y * b2f_hi(p01) + w.z * b2f_hi(p10) + w.w * b2f_hi(p11);
        }
    }
    uint32_t outpk = (uint32_t)f2b(acc0) | ((uint32_t)f2b(acc1) << 16);
    *(uint32_t*)(samp + (size_t)pt * 128 + c2) = outpk;
}

// ================= 256-thread GEMM building blocks =================
__device__ __forceinline__ void stage_tile(const unsigned short* __restrict__ g, int ld,
                                           unsigned short* lds, int wave, int lane) {
    #pragma unroll
    for (int j = 0; j < 4; ++j) {
        int idx = wave * 256 + j * 64 + lane;      // chunk slot index 0..1023
        int r = idx >> 3;
        int cs = idx & 7;
        int cl = cs ^ (r & 7);                     // logical chunk this slot holds
        __builtin_amdgcn_global_load_lds(
            (const __attribute__((address_space(1))) void*)(g + (size_t)r * ld + cl * 8),
            (__attribute__((address_space(3))) void*)(lds + wave * 2048 + j * 512),
            16, 0, 0);
    }
}

__device__ __forceinline__ frag8 frag_read(const unsigned short* lds, int row, int chunk) {
    return *(const frag8*)(lds + row * 64 + ((chunk ^ (row & 7)) << 3));
}

__device__ __forceinline__ void mma_tile(const unsigned short* As, const unsigned short* Bs,
                                         int wm, int wn, int lane, f32x4 (&acc)[4][4]) {
    int lm = lane & 15, lq = lane >> 4;
    #pragma unroll
    for (int kk = 0; kk < 2; ++kk) {
        frag8 a[4], b[4];
        #pragma unroll
        for (int t = 0; t < 4; ++t) a[t] = frag_read(As, wm * 64 + t * 16 + lm, kk * 4 + lq);
        #pragma unroll
        for (int t = 0; t < 4; ++t) b[t] = frag_read(Bs, wn * 64 + t * 16 + lm, kk * 4 + lq);
        #pragma unroll
        for (int tm = 0; tm < 4; ++tm)
            #pragma unroll
            for (int tn = 0; tn < 4; ++tn)
                acc[tm][tn] = __builtin_amdgcn_mfma_f32_16x16x32_bf16(a[tm], b[tn], acc[tm][tn], 0, 0, 0);
    }
}

// ======== counted-vmcnt 2-deep pipeline (T4): loads stay in flight ACROSS barriers ========
template <int KT>
__device__ __forceinline__ void gemm_loop_pipe(const unsigned short* __restrict__ A, int ldA,
                                               const unsigned short* __restrict__ B, int ldB,
                                               unsigned short (*As)[BM * BK],
                                               unsigned short (*Bs)[BN * BK],
                                               int wave, int lane, int wm, int wn,
                                               f32x4 (&acc)[4][4]) {
    stage_tile(A, ldA, As[0], wave, lane);
    stage_tile(B, ldB, Bs[0], wave, lane);
    if (KT > 1) {
        stage_tile(A + BK, ldA, As[1], wave, lane);
        stage_tile(B + BK, ldB, Bs[1], wave, lane);
    }
    #pragma unroll
    for (int kt = 0; kt < KT; ++kt) {
        int cur = kt & 1;
        if (kt + 1 < KT) asm volatile("s_waitcnt vmcnt(8)" ::: "memory");
        else             asm volatile("s_waitcnt vmcnt(0)" ::: "memory");
        __builtin_amdgcn_s_barrier();              // buf[cur] ready for all waves
        mma_tile(As[cur], Bs[cur], wm, wn, lane, acc);
        asm volatile("s_waitcnt lgkmcnt(0)" ::: "memory");
        __builtin_amdgcn_s_barrier();              // all waves done reading buf[cur]
        if (kt + 2 < KT) {                         // refill buf[cur] for tile kt+2
            stage_tile(A + (kt + 2) * BK, ldA, As[cur], wave, lane);
            stage_tile(B + (kt + 2) * BK, ldB, Bs[cur], wave, lane);
        }
    }
}

// ---------------- H1 slice builder (cooperative, cvt_pk) — 2 chunks/thread ----------------
__device__ __forceinline__ void build_h1_2(const float* __restrict__ wls, float x, float y, float z,
                                           int r, int c0, int kt, unsigned short* __restrict__ As) {
    #pragma unroll
    for (int j = 0; j < 2; ++j) {
        int cl = c0 + j;
        const float* wp = wls + kt * 64 + cl * 8;      // wave-uniform -> LDS broadcast
        float4 a0l = *(const float4*)(wp),       a0h = *(const float4*)(wp + 4);
        float4 a1l = *(const float4*)(wp + 256), a1h = *(const float4*)(wp + 260);
        float4 a2l = *(const float4*)(wp + 512), a2h = *(const float4*)(wp + 516);
        float4 bbl = *(const float4*)(wp + 768), bbh = *(const float4*)(wp + 772);
        float v0 = fmaxf(x * a0l.x + y * a1l.x + z * a2l.x + bbl.x, 0.f);
        float v1 = fmaxf(x * a0l.y + y * a1l.y + z * a2l.y + bbl.y, 0.f);
        float v2 = fmaxf(x * a0l.z + y * a1l.z + z * a2l.z + bbl.z, 0.f);
        float v3 = fmaxf(x * a0l.w + y * a1l.w + z * a2l.w + bbl.w, 0.f);
        float v4 = fmaxf(x * a0h.x + y * a1h.x + z * a2h.x + bbh.x, 0.f);
        float v5 = fmaxf(x * a0h.y + y * a1h.y + z * a2h.y + bbh.y, 0.f);
        float v6 = fmaxf(x * a0h.z + y * a1h.z + z * a2h.z + bbh.z, 0.f);
        float v7 = fmaxf(x * a0h.w + y * a1h.w + z * a2h.w + bbh.w, 0.f);
        uint32_t q0 = cvtpk_bf16(v0, v1), q1 = cvtpk_bf16(v2, v3);
        uint32_t q2 = cvtpk_bf16(v4, v5), q3 = cvtpk_bf16(v6, v7);
        *(uint4*)(As + r * 64 + ((cl ^ (r & 7)) << 3)) = make_uint4(q0, q1, q2, q3);
    }
}

// ---------------- fused pe1+pe2, BM=64 x BN=256, grid 1600 + T4 counted-vmcnt B-pipeline ----------------
// R7 baseline ~42 µs with full-drain barriers; this round applies the counted-vmcnt schedule
// (the only intervention that moved the ~300 TF floor on conv1/pe3): Bs double-buffered,
// As single (VALU-built, ordered via lgkmcnt(0) before the barrier), vmcnt never drained
// to 0 inside the loop.
__global__ __launch_bounds__(256) void k_pe12(const float* __restrict__ bev,
                                              const float* __restrict__ pw1,
                                              const float* __restrict__ pb1,
                                              const unsigned short* __restrict__ Bt,
                                              const float* __restrict__ bias,
                                              unsigned short* __restrict__ H2) {
    __shared__ unsigned short As[64 * BK];         // 8 KB (single: rebuilt per kt by VALU)
    __shared__ unsigned short Bs[2][256 * BK];     // 64 KB (double-buffered)
    __shared__ __align__(16) float wls[4 * 256];   // rows 0..2 = w1, row 3 = b1 (4 KB)
    __shared__ float bevs[3 * 64];                 // 0.75 KB
    int t = threadIdx.x, lane = t & 63, wave = t >> 6;
    int m0 = blockIdx.x * 64;
    {   // stage w1 (3x256) + b1 (256): 1024 floats, 4 per thread
        int i = t * 4;
        int j = i >> 8, c = i & 255;
        float4 v = (j < 3) ? *(const float4*)(pw1 + j * 256 + c)
                           : *(const float4*)(pb1 + c);
        *(float4*)(wls + i) = v;
    }
    if (t < 64) {    // this block's 64 bev rows (point index m = q*4+p, p inner)
        int m = m0 + t;
        int q = m >> 2, p = m & 3;
        int h = q / 160, w = q - h * 160;
        const float* bv = bev + ((size_t)((p * 160 + h) * 160 + w)) * 3;
        bevs[t] = bv[0]; bevs[64 + t] = bv[1]; bevs[128 + t] = bv[2];
    }
    __syncthreads();
    int r = t & 63;                       // this thread's H1 row
    int c0 = (t >> 6) * 2;                // first of its 2 chunks
    float x = bevs[r], y = bevs[64 + r], z = bevs[128 + r];
    int lm = lane & 15, lq = lane >> 4;
    f32x4 acc[4][4] = {};
    // prologue: stage kt0 + kt1 B-tiles (8 loads/wave each; 16 in flight)
    stage_tile(Bt, 256, Bs[0], wave, lane);
    stage_tile(Bt + 128 * 256, 256, Bs[0] + 8192, wave, lane);
    stage_tile(Bt + BK, 256, Bs[1], wave, lane);
    stage_tile(Bt + 128 * 256 + BK, 256, Bs[1] + 8192, wave, lane);
    #pragma unroll
    for (int kt = 0; kt < 4; ++kt) {
        int cur = kt & 1;
        build_h1_2(wls, x, y, z, r, c0, kt, As);   // VALU overlaps in-flight loads
        asm volatile("s_waitcnt lgkmcnt(0)" ::: "memory");   // As writes visible
        if (kt + 1 < 4) asm volatile("s_waitcnt vmcnt(8)" ::: "memory");
        else            asm volatile("s_waitcnt vmcnt(0)" ::: "memory");
        __builtin_amdgcn_s_barrier();              // As + Bs[cur] ready for all waves
        #pragma unroll
        for (int kk = 0; kk < 2; ++kk) {
            int ch = kk * 4 + lq;
            frag8 a[4], b[4];
            #pragma unroll
            for (int tt = 0; tt < 4; ++tt) a[tt] = frag_read(As, tt * 16 + lm, ch);
            #pragma unroll
            for (int tn = 0; tn < 4; ++tn) b[tn] = frag_read(Bs[cur], wave * 64 + tn * 16 + lm, ch);
            #pragma unroll
            for (int tm = 0; tm < 4; ++tm)
                #pragma unroll
                for (int tn = 0; tn < 4; ++tn)
                    acc[tm][tn] = __builtin_amdgcn_mfma_f32_16x16x32_bf16(a[tm], b[tn], acc[tm][tn], 0, 0, 0);
        }
        asm volatile("s_waitcnt lgkmcnt(0)" ::: "memory");   // mma's ds_reads done
        __builtin_amdgcn_s_barrier();              // all waves done with As/Bs[cur]
        if (kt + 2 < 4) {                          // refill Bs[cur] for tile kt+2
            stage_tile(Bt + (kt + 2) * BK, 256, Bs[cur], wave, lane);
            stage_tile(Bt + 128 * 256 + (kt + 2) * BK, 256, Bs[cur] + 8192, wave, lane);
        }
    }
    #pragma unroll
    for (int tn = 0; tn < 4; ++tn) {
        int n = wave * 64 + tn * 16 + lm;
        float bn = bias[n];
        #pragma unroll
        for (int tm = 0; tm < 4; ++tm) {
            int mb = m0 + tm * 16 + lq * 4;
            #pragma unroll
            for (int rr = 0; rr < 4; ++rr)
                H2[(size_t)(mb + rr) * 256 + n] = f2b(fmaxf(acc[tm][tn][rr] + bn, 0.f));
        }
    }
}

// ---------------- pe3: X = bf16(samp + H2 @ W3T^T + b3), counted-vmcnt pipeline ----------------
__global__ __launch_bounds__(256) void k_gemm_pe3(const unsigned short* __restrict__ A,
                                                  const unsigned short* __restrict__ Bt,
                                                  const float* __restrict__ bias,
                                                  const unsigned short* __restrict__ samp,
                                                  unsigned short* __restrict__ X) {
    __shared__ unsigned short As[2][BM * BK], Bs[2][BN * BK];
    int lane = threadIdx.x & 63, wave = threadIdx.x >> 6;
    int wm = wave >> 1, wn = wave & 1;
    int m0 = blockIdx.x * BM;
    f32x4 acc[4][4] = {};
    gemm_loop_pipe<4>(A + (size_t)m0 * 256, 256, Bt, 256, As, Bs, wave, lane, wm, wn, acc);
    int lm = lane & 15, lq = lane >> 4;
    #pragma unroll
    for (int tn = 0; tn < 4; ++tn) {
        int n = wn * 64 + tn * 16 + lm;
        float bn = bias[n];
        #pragma unroll
        for (int tm = 0; tm < 4; ++tm) {
            int mb = m0 + wm * 64 + tm * 16 + lq * 4;
            #pragma unroll
            for (int rr = 0; rr < 4; ++rr) {
                size_t off = (size_t)(mb + rr) * 128 + n;
                X[off] = f2b(acc[tm][tn][rr] + bn + b2f_bits(samp[off]));
            }
        }
    }
}

// ---------------- conv GEMM (counted-vmcnt pipeline) -> bf16 Y + optional stats ----------------
template <int K, bool STATS>
__global__ __launch_bounds__(256) void k_gemm_conv(const unsigned short* __restrict__ A,
                                                   const unsigned short* __restrict__ Bt,
                                                   const float* __restrict__ bias,
                                                   unsigned short* __restrict__ Y, int ldY,
                                                   float* __restrict__ st, int C) {
    __shared__ unsigned short As[2][BM * BK], Bs[2][BN * BK];
    int lane = threadIdx.x & 63, wave = threadIdx.x >> 6;
    int wm = wave >> 1, wn = wave & 1;
    int m0 = blockIdx.x * BM, n0 = blockIdx.y * BN;
    f32x4 acc[4][4] = {};
    gemm_loop_pipe<K / BK>(A + (size_t)m0 * K, K, Bt + (size_t)n0 * K, K,
                           As, Bs, wave, lane, wm, wn, acc);
    int lm = lane & 15, lq = lane >> 4;
    #pragma unroll
    for (int tn = 0; tn < 4; ++tn) {
        int n = n0 + wn * 64 + tn * 16 + lm;
        float bn = bias[n];
        float s1 = 0.f, s2 = 0.f;
        #pragma unroll
        for (int tm = 0; tm < 4; ++tm) {
            int mb = m0 + wm * 64 + tm * 16 + lq * 4;
            #pragma unroll
            for (int rr = 0; rr < 4; ++rr) {
                float v = acc[tm][tn][rr] + bn;
                Y[(size_t)(mb + rr) * ldY + n] = f2b(v);
                if (STATS) { s1 += v; s2 += v * v; }
            }
        }
        if (STATS) {
            s1 += __shfl_xor(s1, 16); s1 += __shfl_xor(s1, 32);
            s2 += __shfl_xor(s2, 16); s2 += __shfl_xor(s2, 32);
            if (lq == 0) { atomicAdd(&st[n], s1); atomicAdd(&st[C + n], s2); }
        }
    }
}

// ---------------- conv3 (counted-vmcnt pipeline) -> out f32 [128][25600] ----------------
__global__ __launch_bounds__(256) void k_gemm_conv3(const unsigned short* __restrict__ A,
                                                    const unsigned short* __restrict__ Bt,
                                                    const float* __restrict__ bias,
                                                    float* __restrict__ out) {
    __shared__ unsigned short As[2][BM * BK], Bs[2][BN * BK];
    int lane = threadIdx.x & 63, wave = threadIdx.x >> 6;
    int wm = wave >> 1, wn = wave & 1;
    int m0 = blockIdx.x * BM;
    f32x4 acc[4][4] = {};
    gemm_loop_pipe<2>(A + (size_t)m0 * 128, 128, Bt, 128, As, Bs, wave, lane, wm, wn, acc);
    int lm = lane & 15, lq = lane >> 4;
    #pragma unroll
    for (int tn = 0; tn < 4; ++tn) {
        int n = wn * 64 + tn * 16 + lm;
        float bn = bias[n];
        #pragma unroll
        for (int tm = 0; tm < 4; ++tm) {
            int mb = m0 + wm * 64 + tm * 16 + lq * 4;
            float4 pk;
            pk.x = acc[tm][tn][0] + bn;
            pk.y = acc[tm][tn][1] + bn;
            pk.z = acc[tm][tn][2] + bn;
            pk.w = acc[tm][tn][3] + bn;
            *(float4*)(out + (size_t)n * 25600 + mb) = pk;
        }
    }
}

// -------- norm+gelu with inline finalize (mean/rsqrt derived from raw sums) --------
__global__ void k_normgelu8f(const unsigned short* __restrict__ Y, const float* __restrict__ st,
                             unsigned short* __restrict__ X2, int Cmask, int C, float inv_n,
                             int total8) {
    int i8 = blockIdx.x * 256 + threadIdx.x;
    if (i8 >= total8) return;
    int e0 = i8 * 8;
    int c = e0 & Cmask;
    uint4 y = *(const uint4*)(Y + e0);
    float4 s1a = *(const float4*)(st + c);
    float4 s1b = *(const float4*)(st + c + 4);
    float4 s2a = *(const float4*)(st + C + c);
    float4 s2b = *(const float4*)(st + C + c + 4);
    float mu[8] = { s1a.x * inv_n, s1a.y * inv_n, s1a.z * inv_n, s1a.w * inv_n,
                    s1b.x * inv_n, s1b.y * inv_n, s1b.z * inv_n, s1b.w * inv_n };
    float sq[8] = { s2a.x, s2a.y, s2a.z, s2a.w, s2b.x, s2b.y, s2b.z, s2b.w };
    float rs[8];
    #pragma unroll
    for (int j = 0; j < 8; ++j) rs[j] = rsqrtf(sq[j] * inv_n - mu[j] * mu[j] + 1e-5f);
    const float is2 = 0.70710678118654752f;
    unsigned int yw[4] = {y.x, y.y, y.z, y.w};
    unsigned int ow[4];
    #pragma unroll
    for (int j = 0; j < 4; ++j) {
        float v0 = (b2f_bits((unsigned short)(yw[j] & 0xffffu)) - mu[j * 2]) * rs[j * 2];
        float v1 = (b2f_bits((unsigned short)(yw[j] >> 16)) - mu[j * 2 + 1]) * rs[j * 2 + 1];
        float g0 = 0.5f * v0 * (1.f + erff(v0 * is2));
        float g1 = 0.5f * v1 * (1.f + erff(v1 * is2));
        ow[j] = (uint32_t)f2b(g0) | ((uint32_t)f2b(g1) << 16);
    }
    *(uint4*)(X2 + e0) = make_uint4(ow[0], ow[1], ow[2], ow[3]);
}

// ---------------- launch ----------------
extern "C" void kernel_launch(void* const* d_in, const int* in_sizes, int n_in,
                              void* d_out, int out_size, void* d_ws, size_t ws_size,
                              hipStream_t stream) {
    (void)in_sizes; (void)n_in; (void)out_size; (void)ws_size;
    const float* feat = (const float*)d_in[0];
    const float* l2i  = (const float*)d_in[1];
    const float* bev  = (const float*)d_in[2];
    const float* pw1  = (const float*)d_in[3];
    const float* pb1  = (const float*)d_in[4];
    const float* pw2  = (const float*)d_in[5];
    const float* pb2  = (const float*)d_in[6];
    const float* pw3  = (const float*)d_in[7];
    const float* pb3  = (const float*)d_in[8];
    const float* c1w  = (const float*)d_in[9];
    const float* c1b  = (const float*)d_in[10];
    const float* c2w  = (const float*)d_in[11];
    const float* c2b  = (const float*)d_in[12];
    const float* c3w  = (const float*)d_in[13];
    const float* c3b  = (const float*)d_in[14];
    float* outp = (float*)d_out;
    char* ws = (char*)d_ws;

    // ---- workspace layout (bytes), peak ~148.6 MB ----
    unsigned short* featT = (unsigned short*)(ws + 0);          //  4,325,376 + 23,040 pad
    unsigned short* W2Tb  = (unsigned short*)(ws + 4348416);    //    131,072 [256][256] bf16 [o][k]
    unsigned short* W3Tb  = (unsigned short*)(ws + 4479488);    //     65,536 [128][256]
    unsigned short* C1Wb  = (unsigned short*)(ws + 4545024);    //    524,288 [512][512]
    unsigned short* C2Wb  = (unsigned short*)(ws + 5069312);    //    131,072 [128][512]
    unsigned short* C3Wb  = (unsigned short*)(ws + 5200384);    //     32,768 [128][128]
    float* stats          = (float*)(ws + 5233152);             //     10,240
    int*    poff          = (int*)(ws + 5247488);               //  2,457,600 [6][102400]
    float4* pwts          = (float4*)(ws + 7705088);            //  9,830,400 [6][102400]
    char* BUF1 = ws + 17535488;   // 52,428,800: X bf16 -> Y2 bf16 + X3 bf16
    char* BUF2 = ws + 69964288;   // 52,428,800: H2 bf16 -> Y1 bf16
    char* BUF3 = ws + 122393088;  // 26,214,400: samp bf16 -> X2 bf16

    float* st512 = stats;          // 1024 f (sums + sumsq)
    float* st128 = stats + 2048;   // 256 f

    unsigned short* H2   = (unsigned short*)BUF2;
    unsigned short* samp = (unsigned short*)BUF3;
    unsigned short* X    = (unsigned short*)BUF1;
    unsigned short* Y1   = (unsigned short*)BUF2;               // after H2 dead (conv1)
    unsigned short* X2   = (unsigned short*)BUF3;               // after samp dead (normgelu1)
    unsigned short* Y2   = (unsigned short*)BUF1;               // after X dead (conv2)
    unsigned short* X3   = (unsigned short*)(BUF1 + 6553600);

    // merged prep: projection + featT transpose + casts + stats zero
    k_prep<<<4393, 256, 0, stream>>>(feat, pw2, pw3, c1w, c2w, c3w, l2i, bev,
                                     featT, W2Tb, W3Tb, C1Wb, C2Wb, C3Wb, stats,
                                     poff, pwts);

    // gather-only sampling
    k_sample2<<<25600, 256, 0, stream>>>(featT, poff, pwts, samp);

    // PE MLP: fused pe1+pe2 (BM=64 x BN=256 + T4 pipe), then pe3 (pipelined)
    k_pe12<<<1600, 256, 0, stream>>>(bev, pw1, pb1, W2Tb, pb2, H2);
    k_gemm_pe3<<<dim3(800, 1), 256, 0, stream>>>(H2, W3Tb, pb3, samp, X);

    // conv1 (512->512, pipelined) + fused stats
    k_gemm_conv<512, true><<<dim3(200, 4), 256, 0, stream>>>(X, C1Wb, c1b, Y1, 512, st512, 512);
    k_normgelu8f<<<6400, 256, 0, stream>>>(Y1, st512, X2, 511, 512, 1.f / 25600.f, 1638400);

    // conv2 (512->128, pipelined, BN=128) + fused stats, then norm+gelu
    k_gemm_conv<512, true><<<dim3(200, 1), 256, 0, stream>>>(X2, C2Wb, c2b, Y2, 128, st128, 128);
    k_normgelu8f<<<1600, 256, 0, stream>>>(Y2, st128, X3, 127, 128, 1.f / 25600.f, 409600);

    // conv3 (128->128, pipelined) -> out f32 [128][25600]
    k_gemm_conv3<<<200, 256, 0, stream>>>(X3, C3Wb, c3b, outp);
}